// Round 3
// baseline (51.658 us; speedup 1.0000x reference)
//
#include <hip/hip_runtime.h>

#define NCH   256
#define FH    64
#define FW    64
#define OUT_H 7
#define OUT_W 7

// ---- Kernel 1: transpose (B,C,H,W) -> (B,H*W,C) into workspace ----
__global__ __launch_bounds__(256) void transpose_kernel(
    const float* __restrict__ fm, float* __restrict__ fmT)
{
    __shared__ float tile[64][65];
    const int hw0 = blockIdx.x * 64;   // 64 tiles of hw
    const int c0  = blockIdx.y * 64;   // 4 tiles of c
    const int b   = blockIdx.z;        // 4 batches
    const int t   = threadIdx.x;
    const int x   = t & 63;
    const int y   = t >> 6;            // 0..3

    const float* src = fm + (((size_t)(b * NCH + c0)) << 12) + hw0;
    #pragma unroll
    for (int r = 0; r < 16; ++r) {
        const int cl = y + r * 4;
        tile[cl][x] = src[((size_t)cl << 12) + x];   // coalesced 256B rows
    }
    __syncthreads();
    float* dst = fmT + ((size_t)((b << 12) + hw0)) * NCH + c0;
    #pragma unroll
    for (int r = 0; r < 16; ++r) {
        const int hwl = y + r * 4;
        dst[(size_t)hwl * NCH + x] = tile[x][hwl];   // coalesced, LDS conflict-free (65 pad)
    }
}

// ---- Kernel 2: one wave per (roi, cell); lane = 4 channels (float4) ----
__global__ __launch_bounds__(256) void roipool_kernel(
    const float* __restrict__ fmT,   // (B, H*W, C)
    const int*   __restrict__ rois,  // (N,5): b,x1,y1,x2,y2
    float*       __restrict__ out)   // (N, C, 7, 7)
{
    const int wv   = threadIdx.x >> 6;
    const int lane = threadIdx.x & 63;
    const int task = blockIdx.x * 4 + wv;      // n*49 + cell
    const int n    = task / 49;
    const int cell = task - n * 49;
    const int i    = cell / OUT_W;
    const int j    = cell - i * OUT_W;

    const int* r  = rois + n * 5;
    const int b   = r[0];
    const int ltx = r[1] >> 4;   // exact: x*(1/16.f) trunc, 0<=x<1024
    const int lty = r[2] >> 4;
    const int rbx = r[3] >> 4;
    const int rby = r[4] >> 4;
    const int h_roi = rby - lty + 1;           // 1..34, bins never empty
    const int w_roi = rbx - ltx + 1;

    const int hs = lty + (i * h_roi) / OUT_H;
    const int he = lty + ((i + 1) * h_roi + OUT_H - 1) / OUT_H;
    const int ws = ltx + (j * w_roi) / OUT_W;
    const int we = ltx + ((j + 1) * w_roi + OUT_W - 1) / OUT_W;

    const float4* base = (const float4*)fmT + ((size_t)b << 18) + lane; // b*4096*64
    float4 m = make_float4(-INFINITY, -INFINITY, -INFINITY, -INFINITY);
    for (int hh = hs; hh < he; ++hh) {
        const float4* rowp = base + ((size_t)hh << 12);   // hh*64*64 float4
        for (int ww = ws; ww < we; ++ww) {
            const float4 v = rowp[(size_t)ww << 6];       // 1KB coalesced load
            m.x = fmaxf(m.x, v.x);
            m.y = fmaxf(m.y, v.y);
            m.z = fmaxf(m.z, v.z);
            m.w = fmaxf(m.w, v.w);
        }
    }
    float* o = out + ((size_t)n * NCH + lane * 4) * (OUT_H * OUT_W) + cell;
    o[0]   = m.x;
    o[49]  = m.y;
    o[98]  = m.z;
    o[147] = m.w;
}

extern "C" void kernel_launch(void* const* d_in, const int* in_sizes, int n_in,
                              void* d_out, int out_size, void* d_ws, size_t ws_size,
                              hipStream_t stream) {
    const float* fm   = (const float*)d_in[0];
    const int*   rois = (const int*)d_in[1];
    float*       out  = (float*)d_out;
    float*       fmT  = (float*)d_ws;          // 16 MB scratch

    // transpose: grid (hw tiles, c tiles, B)
    dim3 tgrid(FH * FW / 64, NCH / 64, 4);
    transpose_kernel<<<tgrid, 256, 0, stream>>>(fm, fmT);

    const int N = in_sizes[1] / 5;             // 256
    const int tasks = N * OUT_H * OUT_W;       // 12544
    roipool_kernel<<<dim3(tasks / 4), 256, 0, stream>>>(fmT, rois, out);
}

// Round 4
// 49.171 us; speedup vs baseline: 1.0506x; 1.0506x over previous
//
#include <hip/hip_runtime.h>

#define NCH   256
#define FH    64
#define FW    64
#define OUT_H 7
#define OUT_W 7

// ---- Kernel 1: transpose (B,C,H,W) -> (B,H*W,C) into workspace ----
__global__ __launch_bounds__(256) void transpose_kernel(
    const float* __restrict__ fm, float* __restrict__ fmT)
{
    __shared__ float tile[64][65];
    const int hw0 = blockIdx.x * 64;   // 64 tiles of hw
    const int c0  = blockIdx.y * 64;   // 4 tiles of c
    const int b   = blockIdx.z;        // 4 batches
    const int t   = threadIdx.x;
    const int x   = t & 63;
    const int y   = t >> 6;            // 0..3

    const float* src = fm + (((size_t)(b * NCH + c0)) << 12) + hw0;
    #pragma unroll
    for (int r = 0; r < 16; ++r) {
        const int cl = y + r * 4;
        tile[cl][x] = src[((size_t)cl << 12) + x];   // coalesced
    }
    __syncthreads();
    float* dst = fmT + ((size_t)((b << 12) + hw0)) * NCH + c0;
    #pragma unroll
    for (int r = 0; r < 16; ++r) {
        const int hwl = y + r * 4;
        dst[(size_t)hwl * NCH + x] = tile[x][hwl];   // coalesced, pad-65 conflict-free
    }
}

// ---- Kernel 2: block = (roi, channel-half); wave = cell; lane = 2 channels ----
__global__ __launch_bounds__(1024, 8) void roipool_kernel(
    const float* __restrict__ fmT,   // (B, H*W, C)
    const int*   __restrict__ rois,  // (N,5): b,x1,y1,x2,y2
    float*       __restrict__ out)   // (N, C, 7, 7)
{
    const int n     = blockIdx.x >> 1;
    const int chalf = blockIdx.x & 1;
    const int wv    = threadIdx.x >> 6;      // 0..15
    const int lane  = threadIdx.x & 63;
    const int ch2   = chalf * 64 + lane;     // float2 index within a position

    const int* r  = rois + n * 5;
    const int b   = r[0];
    const int ltx = r[1] >> 4;   // exact: x*(1/16.f) trunc, 0<=x<1024
    const int lty = r[2] >> 4;
    const int rbx = r[3] >> 4;
    const int rby = r[4] >> 4;
    const int h_roi = rby - lty + 1;         // 1..34
    const int w_roi = rbx - ltx + 1;         // bins never empty

    // base in float2 units: ((b<<12) + hh*64 + ww)*128 + ch2
    const float2* base = (const float2*)fmT + (((size_t)b << 12) * 128) + ch2;

    for (int cell = wv; cell < OUT_H * OUT_W; cell += 16) {
        const int i = cell / OUT_W;
        const int j = cell - i * OUT_W;

        const int hs = lty + (i * h_roi) / OUT_H;
        const int he = lty + ((i + 1) * h_roi + OUT_H - 1) / OUT_H;
        const int ws = ltx + (j * w_roi) / OUT_W;
        const int we1 = ltx + ((j + 1) * w_roi + OUT_W - 1) / OUT_W - 1; // last col

        // 6 clamped column offsets (max w-bin width = 6; repeats harmless for max)
        const int w0 = ws;
        const int w1 = (ws + 1 < we1) ? ws + 1 : we1;
        const int w2 = (ws + 2 < we1) ? ws + 2 : we1;
        const int w3 = (ws + 3 < we1) ? ws + 3 : we1;
        const int w4 = (ws + 4 < we1) ? ws + 4 : we1;
        const int w5 = we1;

        float2 m = make_float2(-INFINITY, -INFINITY);
        for (int hh = hs; hh < he; ++hh) {               // wave-uniform bounds
            const float2* rp = base + (size_t)hh * (FW * 128);
            const float2 v0 = rp[(size_t)w0 * 128];      // 6 independent 512B loads
            const float2 v1 = rp[(size_t)w1 * 128];
            const float2 v2 = rp[(size_t)w2 * 128];
            const float2 v3 = rp[(size_t)w3 * 128];
            const float2 v4 = rp[(size_t)w4 * 128];
            const float2 v5 = rp[(size_t)w5 * 128];
            m.x = fmaxf(m.x, v0.x); m.y = fmaxf(m.y, v0.y);
            m.x = fmaxf(m.x, v1.x); m.y = fmaxf(m.y, v1.y);
            m.x = fmaxf(m.x, v2.x); m.y = fmaxf(m.y, v2.y);
            m.x = fmaxf(m.x, v3.x); m.y = fmaxf(m.y, v3.y);
            m.x = fmaxf(m.x, v4.x); m.y = fmaxf(m.y, v4.y);
            m.x = fmaxf(m.x, v5.x); m.y = fmaxf(m.y, v5.y);
        }

        // block's whole output range is contiguous (25 KB) -> assembles in one L2
        float* o = out + (size_t)(n * NCH + ch2 * 2) * (OUT_H * OUT_W) + cell;
        o[0]              = m.x;
        o[OUT_H * OUT_W]  = m.y;
    }
}

extern "C" void kernel_launch(void* const* d_in, const int* in_sizes, int n_in,
                              void* d_out, int out_size, void* d_ws, size_t ws_size,
                              hipStream_t stream) {
    const float* fm   = (const float*)d_in[0];
    const int*   rois = (const int*)d_in[1];
    float*       out  = (float*)d_out;
    float*       fmT  = (float*)d_ws;          // 16 MB scratch

    dim3 tgrid(FH * FW / 64, NCH / 64, 4);
    transpose_kernel<<<tgrid, 256, 0, stream>>>(fm, fmT);

    const int N = in_sizes[1] / 5;             // 256
    roipool_kernel<<<dim3(N * 2), 1024, 0, stream>>>(fmT, rois, out);
}